// Round 6
// baseline (246.607 us; speedup 1.0000x reference)
//
#include <hip/hip_runtime.h>

#define N_NODES 100000
#define N_EDGES 1000000
#define IN_CH 166
#define HID 128
#define M_PAD 100032   // 1563 * 64
#define BSHIFT 9
#define NBUCK 196      // ceil(100000 / 512)

typedef unsigned short u16;
typedef unsigned int u32;
typedef __attribute__((ext_vector_type(8))) short short8;
typedef __attribute__((ext_vector_type(4))) float f32x4;

static __device__ __forceinline__ u16 f2bf(float f) {
    unsigned u = __float_as_uint(f);
    u += 0x7FFF + ((u >> 16) & 1);   // RNE
    return (u16)(u >> 16);
}
static __device__ __forceinline__ unsigned pk2(float a, float b) {
    return (unsigned)f2bf(a) | ((unsigned)f2bf(b) << 16);
}
static __device__ __forceinline__ float bf_lo(unsigned w) {
    return __uint_as_float(w << 16);
}
static __device__ __forceinline__ float bf_hi(unsigned w) {
    return __uint_as_float(w & 0xFFFF0000u);
}

// ================= graph build: two-level counting sort =================

__global__ __launch_bounds__(256) void k_bincount(const int* __restrict__ dst,
                                                  int* __restrict__ bcnt) {
    __shared__ int cnt[NBUCK];
    const int t = threadIdx.x;
    if (t < NBUCK) cnt[t] = 0;
    __syncthreads();
#pragma unroll
    for (int j = 0; j < 4; ++j) {
        int e4 = blockIdx.x * 1024 + j * 256 + t;
        if (e4 < N_EDGES / 4) {
            int4 d = ((const int4*)dst)[e4];
            atomicAdd(&cnt[d.x >> BSHIFT], 1);
            atomicAdd(&cnt[d.y >> BSHIFT], 1);
            atomicAdd(&cnt[d.z >> BSHIFT], 1);
            atomicAdd(&cnt[d.w >> BSHIFT], 1);
        }
    }
    __syncthreads();
    if (t < NBUCK && cnt[t] > 0) atomicAdd(&bcnt[t], cnt[t]);
}

__global__ __launch_bounds__(256) void k_bucketscan(const int* __restrict__ bcnt,
                                                    int* __restrict__ bucket_base,
                                                    int* __restrict__ gcursor,
                                                    int* __restrict__ offsets) {
    __shared__ int ws[256];
    const int t = threadIdx.x;
    int loc = (t < NBUCK) ? bcnt[t] : 0;
    ws[t] = loc;
    __syncthreads();
    int val = loc;
    for (int stp = 1; stp < 256; stp <<= 1) {
        int other = (t >= stp) ? ws[t - stp] : 0;
        __syncthreads();
        val += other;
        ws[t] = val;
        __syncthreads();
    }
    int excl = val - loc;
    if (t < NBUCK) {
        bucket_base[t] = excl;
        gcursor[t] = excl;
    }
    if (t == 255) bucket_base[NBUCK] = val;
    if (t == 0) offsets[N_NODES] = N_EDGES;
}

// stage entry: (src << 9) | (dst & 511)  -- src < 2^17, local dst < 2^9
__global__ __launch_bounds__(256) void k_scatter(const int* __restrict__ src,
                                                 const int* __restrict__ dst,
                                                 int* __restrict__ gcursor,
                                                 u32* __restrict__ stage) {
    __shared__ int cnt[NBUCK];
    __shared__ int base[NBUCK];
    const int t = threadIdx.x;
    if (t < NBUCK) cnt[t] = 0;
    __syncthreads();

    int4 s4[4], d4[4];
    bool ok[4];
#pragma unroll
    for (int j = 0; j < 4; ++j) {
        int e4 = blockIdx.x * 1024 + j * 256 + t;
        ok[j] = (e4 < N_EDGES / 4);
        if (ok[j]) {
            s4[j] = ((const int4*)src)[e4];
            d4[j] = ((const int4*)dst)[e4];
            atomicAdd(&cnt[d4[j].x >> BSHIFT], 1);
            atomicAdd(&cnt[d4[j].y >> BSHIFT], 1);
            atomicAdd(&cnt[d4[j].z >> BSHIFT], 1);
            atomicAdd(&cnt[d4[j].w >> BSHIFT], 1);
        }
    }
    __syncthreads();
    if (t < NBUCK && cnt[t] > 0) base[t] = atomicAdd(&gcursor[t], cnt[t]);
    __syncthreads();

#pragma unroll
    for (int j = 0; j < 4; ++j) {
        if (ok[j]) {
            const int ss[4] = {s4[j].x, s4[j].y, s4[j].z, s4[j].w};
            const int dd[4] = {d4[j].x, d4[j].y, d4[j].z, d4[j].w};
#pragma unroll
            for (int q = 0; q < 4; ++q) {
                int b = dd[q] >> BSHIFT;
                int r = atomicSub(&cnt[b], 1) - 1;
                stage[base[b] + r] = ((u32)ss[q] << 9) | (u32)(dd[q] & 511);
            }
        }
    }
}

__global__ __launch_bounds__(256) void k_csr(const u32* __restrict__ stage,
                                             const int* __restrict__ bucket_base,
                                             int* __restrict__ offsets,
                                             int* __restrict__ ssrc) {
    __shared__ int cnt[512];
    __shared__ int ws[256];
    const int t = threadIdx.x;
    const int b = blockIdx.x;
    const int nb0 = b << BSHIFT;
    const int nn = min(512, N_NODES - nb0);
    const int e0 = bucket_base[b];
    const int m = bucket_base[b + 1] - e0;

    cnt[t] = 0;
    cnt[t + 256] = 0;
    __syncthreads();

    for (int i = t; i < m; i += 256) {
        u32 pr = stage[e0 + i];
        atomicAdd(&cnt[pr & 511], 1);
    }
    __syncthreads();

    int c0 = cnt[2 * t];
    int c1 = cnt[2 * t + 1];
    int loc = c0 + c1;
    ws[t] = loc;
    __syncthreads();
    int val = loc;
    for (int stp = 1; stp < 256; stp <<= 1) {
        int other = (t >= stp) ? ws[t - stp] : 0;
        __syncthreads();
        val += other;
        ws[t] = val;
        __syncthreads();
    }
    int p0 = e0 + (val - loc);
    int p1 = p0 + c0;
    if (2 * t < nn) offsets[nb0 + 2 * t] = p0;
    if (2 * t + 1 < nn) offsets[nb0 + 2 * t + 1] = p1;
    cnt[2 * t] = p0;
    cnt[2 * t + 1] = p1;
    __syncthreads();

    for (int i = t; i < m; i += 256) {
        u32 pr = stage[e0 + i];
        int p = atomicAdd(&cnt[pr & 511], 1);
        ssrc[p] = (int)(pr >> 9);
    }
}

// ---------------- weight prep: Wl|Wr -> bf16 MFMA fragments ----------------

__global__ __launch_bounds__(64) void k_wprep(const float* __restrict__ Wl,
                                              const float* __restrict__ Wr,
                                              int Kact, u16* __restrict__ wf) {
    int lane = threadIdx.x;
    int kt = blockIdx.x >> 4;
    int ct = blockIdx.x & 15;
    int col = ct * 16 + (lane & 15);
    const float* W = (col < 128) ? Wl : Wr;
    int wcol = col & 127;
    float v[8];
#pragma unroll
    for (int j = 0; j < 8; ++j) {
        int row = kt * 32 + (lane >> 4) * 8 + j;
        v[j] = (row < Kact) ? W[(size_t)row * 128 + wcol] : 0.f;
    }
    int4 o;
    o.x = pk2(v[0], v[1]);
    o.y = pk2(v[2], v[3]);
    o.z = pk2(v[4], v[5]);
    o.w = pk2(v[6], v[7]);
    *(int4*)(wf + ((size_t)blockIdx.x * 64 + lane) * 8) = o;
}

// ---------------- MFMA projection: swapped operands ----------------------
// acc[rt][c] = mfma(bf[c], af[rt], acc): D tile = (in @ W)^T, so lane&15 =
// node row, (lane>>4)*4+i = output col -> 4 consecutive cols per lane ->
// packed int2 stores. 8 waves: rg = wv&1 (32 rows), cg = wv>>1 (64 cols).

static __device__ __forceinline__ void proj_epilogue(f32x4 acc[2][4],
                                                     const float* __restrict__ bias,
                                                     u16* __restrict__ y,
                                                     u16* __restrict__ rb,
                                                     int n0, int rg, int cg,
                                                     int r16, int kq) {
    if (cg < 2) {
#pragma unroll
        for (int rt = 0; rt < 2; ++rt) {
            size_t node = (size_t)(n0 + rg * 32 + rt * 16 + r16);
#pragma unroll
            for (int c = 0; c < 4; ++c) {
                int col = cg * 64 + c * 16 + kq * 4;
                int2 ov;
                ov.x = pk2(acc[rt][c][0], acc[rt][c][1]);
                ov.y = pk2(acc[rt][c][2], acc[rt][c][3]);
                *(int2*)(y + node * 128 + col) = ov;
            }
        }
    } else {
#pragma unroll
        for (int rt = 0; rt < 2; ++rt) {
            size_t node = (size_t)(n0 + rg * 32 + rt * 16 + r16);
#pragma unroll
            for (int c = 0; c < 4; ++c) {
                int col = (cg - 2) * 64 + c * 16 + kq * 4;
                float4 bv = *(const float4*)&bias[col];
                int2 ov;
                ov.x = pk2(acc[rt][c][0] + bv.x, acc[rt][c][1] + bv.y);
                ov.y = pk2(acc[rt][c][2] + bv.z, acc[rt][c][3] + bv.w);
                *(int2*)(rb + node * 128 + col) = ov;
            }
        }
    }
}

// layer 0: fp32 x [N,166] staged to bf16 LDS (K padded to 192)
__global__ __launch_bounds__(512, 4) void k_projmm0(const float* __restrict__ in,
                                                    const u16* __restrict__ wf,
                                                    const float* __restrict__ bias,
                                                    u16* __restrict__ y,
                                                    u16* __restrict__ rb) {
    constexpr int KP = 192;
    constexpr int STR = KP + 8;     // 200 u16 = 400 B row stride (16B-mult)
    __shared__ u16 sA[64 * STR];
    const int tid = threadIdx.x;
    const int n0 = blockIdx.x * 64;

    // 48 4-col units per row; unit<=40 full, unit 41 = cols 164..165
#pragma unroll
    for (int it = 0; it < 6; ++it) {
        int c = it * 512 + tid;
        int row = c / 48;
        int unit = c - row * 48;
        int gr = n0 + row;
        float2 a = {0.f, 0.f}, b = {0.f, 0.f};
        if (gr < N_NODES) {
            int k0 = unit * 4;
            const float* rp = in + (size_t)gr * IN_CH + k0;
            if (k0 + 3 < IN_CH) {
                a = *(const float2*)rp;
                b = *(const float2*)(rp + 2);
            } else if (k0 < IN_CH) {
                a = *(const float2*)rp;   // cols 164,165
            }
        }
        int2 o;
        o.x = pk2(a.x, a.y);
        o.y = pk2(b.x, b.y);
        *(int2*)(&sA[row * STR + unit * 4]) = o;
    }
    __syncthreads();

    const int wv = tid >> 6;
    const int lane = tid & 63;
    const int rg = wv & 1;
    const int cg = wv >> 1;
    const int r16 = lane & 15;
    const int kq = lane >> 4;

    f32x4 acc[2][4];
#pragma unroll
    for (int a = 0; a < 2; ++a)
#pragma unroll
        for (int b = 0; b < 4; ++b) acc[a][b] = (f32x4){0.f, 0.f, 0.f, 0.f};

#pragma unroll
    for (int kt = 0; kt < KP / 32; ++kt) {
        short8 af[2], bf[4];
#pragma unroll
        for (int rt = 0; rt < 2; ++rt)
            af[rt] = *(const short8*)(&sA[(rg * 32 + rt * 16 + r16) * STR + kt * 32 + kq * 8]);
#pragma unroll
        for (int c = 0; c < 4; ++c)
            bf[c] = *(const short8*)(wf + (((size_t)(kt * 16 + cg * 4 + c) * 64 + lane) * 8));
#pragma unroll
        for (int rt = 0; rt < 2; ++rt)
#pragma unroll
            for (int c = 0; c < 4; ++c)
                acc[rt][c] = __builtin_amdgcn_mfma_f32_16x16x32_bf16(bf[c], af[rt], acc[rt][c], 0, 0, 0);
    }
    proj_epilogue(acc, bias, y, rb, n0, rg, cg, r16, kq);
}

// layer 1: bf16 input [M_PAD,128], fragments loaded straight from global
__global__ __launch_bounds__(512, 4) void k_projmm1(const u16* __restrict__ in,
                                                    const u16* __restrict__ wf,
                                                    const float* __restrict__ bias,
                                                    u16* __restrict__ y,
                                                    u16* __restrict__ rb) {
    constexpr int KP = 128;
    const int tid = threadIdx.x;
    const int n0 = blockIdx.x * 64;
    const int wv = tid >> 6;
    const int lane = tid & 63;
    const int rg = wv & 1;
    const int cg = wv >> 1;
    const int r16 = lane & 15;
    const int kq = lane >> 4;

    const u16* arow = in + (size_t)(n0 + rg * 32 + r16) * KP + kq * 8;

    f32x4 acc[2][4];
#pragma unroll
    for (int a = 0; a < 2; ++a)
#pragma unroll
        for (int b = 0; b < 4; ++b) acc[a][b] = (f32x4){0.f, 0.f, 0.f, 0.f};

#pragma unroll
    for (int kt = 0; kt < KP / 32; ++kt) {
        short8 af[2], bf[4];
#pragma unroll
        for (int rt = 0; rt < 2; ++rt)
            af[rt] = *(const short8*)(arow + (size_t)rt * 16 * KP + kt * 32);
#pragma unroll
        for (int c = 0; c < 4; ++c)
            bf[c] = *(const short8*)(wf + (((size_t)(kt * 16 + cg * 4 + c) * 64 + lane) * 8));
#pragma unroll
        for (int rt = 0; rt < 2; ++rt)
#pragma unroll
            for (int c = 0; c < 4; ++c)
                acc[rt][c] = __builtin_amdgcn_mfma_f32_16x16x32_bf16(bf[c], af[rt], acc[rt][c], 0, 0, 0);
    }
    proj_epilogue(acc, bias, y, rb, n0, rg, cg, r16, kq);
}

// ---------------- aggregation: h = relu(mean_gather(yb) + rb), bf16 -------
// one 16-lane group per node: 4 nodes/wave, 16 nodes/block.

__global__ __launch_bounds__(256) void k_aggb(const u16* __restrict__ yb,
                                              const u16* __restrict__ rb,
                                              const int* __restrict__ offsets,
                                              const int* __restrict__ ssrc,
                                              u16* __restrict__ h) {
    const int lane = threadIdx.x & 63;
    const int wv = threadIdx.x >> 6;
    const int g = lane >> 4;
    const int i = lane & 15;
    const int node = blockIdx.x * 16 + wv * 4 + g;
    const int off0 = offsets[node];
    const int deg = offsets[node + 1] - off0;

    float acc[8] = {0.f, 0.f, 0.f, 0.f, 0.f, 0.f, 0.f, 0.f};

    int e = 0;
    for (; e + 1 < deg; e += 2) {
        int s0 = ssrc[off0 + e];
        int s1 = ssrc[off0 + e + 1];
        int4 v0 = *(const int4*)(yb + (size_t)s0 * 128 + i * 8);
        int4 v1 = *(const int4*)(yb + (size_t)s1 * 128 + i * 8);
        const unsigned* w0 = (const unsigned*)&v0;
        const unsigned* w1 = (const unsigned*)&v1;
#pragma unroll
        for (int q = 0; q < 4; ++q) {
            acc[q * 2]     += bf_lo(w0[q]) + bf_lo(w1[q]);
            acc[q * 2 + 1] += bf_hi(w0[q]) + bf_hi(w1[q]);
        }
    }
    if (e < deg) {
        int s0 = ssrc[off0 + e];
        int4 v0 = *(const int4*)(yb + (size_t)s0 * 128 + i * 8);
        const unsigned* w0 = (const unsigned*)&v0;
#pragma unroll
        for (int q = 0; q < 4; ++q) {
            acc[q * 2]     += bf_lo(w0[q]);
            acc[q * 2 + 1] += bf_hi(w0[q]);
        }
    }

    float inv = 1.f / (float)max(deg, 1);
    int4 rv = *(const int4*)(rb + (size_t)node * 128 + i * 8);
    const unsigned* rw = (const unsigned*)&rv;
    float o[8];
#pragma unroll
    for (int q = 0; q < 4; ++q) {
        o[q * 2]     = fmaxf(acc[q * 2] * inv + bf_lo(rw[q]), 0.f);
        o[q * 2 + 1] = fmaxf(acc[q * 2 + 1] * inv + bf_hi(rw[q]), 0.f);
    }
    int4 ov;
    ov.x = pk2(o[0], o[1]);
    ov.y = pk2(o[2], o[3]);
    ov.z = pk2(o[4], o[5]);
    ov.w = pk2(o[6], o[7]);
    *(int4*)(h + (size_t)node * 128 + i * 8) = ov;
}

// ---------------- layer 2 projection (bf16 h -> 2ch) ----------------

__global__ __launch_bounds__(256) void k_proj2b(const u16* __restrict__ h,
                                                const float* __restrict__ Wl,
                                                const float* __restrict__ Wr,
                                                const float* __restrict__ bias,
                                                float* __restrict__ z,
                                                float* __restrict__ r2) {
    const int lane = threadIdx.x & 63;
    const int node = blockIdx.x * 4 + (threadIdx.x >> 6);
    unsigned hv = *(const unsigned*)(h + (size_t)node * 128 + lane * 2);
    float h0 = bf_lo(hv);
    float h1 = bf_hi(hv);
    float4 wl = *(const float4*)&Wl[lane * 4];
    float4 wr = *(const float4*)&Wr[lane * 4];
    float zl0 = h0 * wl.x + h1 * wl.z;
    float zl1 = h0 * wl.y + h1 * wl.w;
    float zr0 = h0 * wr.x + h1 * wr.z;
    float zr1 = h0 * wr.y + h1 * wr.w;
    for (int d = 32; d; d >>= 1) {
        zl0 += __shfl_xor(zl0, d);
        zl1 += __shfl_xor(zl1, d);
        zr0 += __shfl_xor(zr0, d);
        zr1 += __shfl_xor(zr1, d);
    }
    if (lane == 0) {
        z[node * 2 + 0] = zl0;
        z[node * 2 + 1] = zl1;
        r2[node * 2 + 0] = zr0 + bias[0];
        r2[node * 2 + 1] = zr1 + bias[1];
    }
}

// ---------------- layer 2 aggregation (2 channels) ----------------

__global__ __launch_bounds__(256) void k_agg2(const float* __restrict__ z,
                                              const float* __restrict__ r2,
                                              const int* __restrict__ offsets,
                                              const int* __restrict__ ssrc,
                                              float* __restrict__ out) {
    int n = blockIdx.x * 256 + threadIdx.x;
    if (n >= N_NODES) return;
    int off0 = offsets[n];
    int off1 = offsets[n + 1];
    float a0 = 0.f, a1 = 0.f;
    for (int e = off0; e < off1; ++e) {
        int s = ssrc[e];
        a0 += z[s * 2];
        a1 += z[s * 2 + 1];
    }
    float inv = 1.0f / (float)max(off1 - off0, 1);
    out[n * 2 + 0] = a0 * inv + r2[n * 2 + 0];
    out[n * 2 + 1] = a1 * inv + r2[n * 2 + 1];
}

// ---------------- launcher ----------------

extern "C" void kernel_launch(void* const* d_in, const int* in_sizes, int n_in,
                              void* d_out, int out_size, void* d_ws, size_t ws_size,
                              hipStream_t stream) {
    const float* x   = (const float*)d_in[0];
    const int*   ei  = (const int*)d_in[1];
    const float* Wl0 = (const float*)d_in[2];
    const float* bl0 = (const float*)d_in[3];
    const float* Wr0 = (const float*)d_in[4];
    const float* Wl1 = (const float*)d_in[5];
    const float* bl1 = (const float*)d_in[6];
    const float* Wr1 = (const float*)d_in[7];
    const float* Wl2 = (const float*)d_in[8];
    const float* bl2 = (const float*)d_in[9];
    const float* Wr2 = (const float*)d_in[10];
    float* out = (float*)d_out;

    const int* srcp = ei;
    const int* dstp = ei + N_EDGES;

    char* ws = (char*)d_ws;
    size_t off = 0;
    auto alloc = [&](size_t bytes) -> void* {
        void* p = ws + off;
        off += (bytes + 255) & ~(size_t)255;
        return p;
    };
    int* bcnt        = (int*)alloc(NBUCK * 4);
    int* bucket_base = (int*)alloc((NBUCK + 1) * 4);
    int* gcursor     = (int*)alloc(NBUCK * 4);
    int* offsets     = (int*)alloc((size_t)(N_NODES + 1) * 4);
    u32* stage       = (u32*)alloc((size_t)N_EDGES * 4);
    int* ssrc        = (int*)alloc((size_t)N_EDGES * 4);
    u16* wf0         = (u16*)alloc((size_t)192 * 256 * 2);
    u16* wf1         = (u16*)alloc((size_t)128 * 256 * 2);
    u16* ybuf        = (u16*)alloc((size_t)M_PAD * 128 * 2);
    u16* rbuf        = (u16*)alloc((size_t)M_PAD * 128 * 2);
    u16* h0          = (u16*)alloc((size_t)M_PAD * 128 * 2);
    u16* h1          = (u16*)alloc((size_t)M_PAD * 128 * 2);
    (void)ws_size; (void)n_in; (void)in_sizes; (void)out_size;

    float* z  = (float*)ybuf;                      // dead after layer-1 aggb
    float* r2 = (float*)((char*)ybuf + 1048576);

    // ---- graph build (two-level counting sort -> CSR by dst) ----
    hipMemsetAsync(bcnt, 0, NBUCK * 4, stream);
    const int NB_SC = (N_EDGES / 4 + 1023) / 1024;   // 245
    k_bincount<<<NB_SC, 256, 0, stream>>>(dstp, bcnt);
    k_bucketscan<<<1, 256, 0, stream>>>(bcnt, bucket_base, gcursor, offsets);
    k_scatter<<<NB_SC, 256, 0, stream>>>(srcp, dstp, gcursor, stage);
    k_csr<<<NBUCK, 256, 0, stream>>>(stage, bucket_base, offsets, ssrc);

    // ---- weight conversion ----
    k_wprep<<<(192 / 32) * 16, 64, 0, stream>>>(Wl0, Wr0, IN_CH, wf0);
    k_wprep<<<(128 / 32) * 16, 64, 0, stream>>>(Wl1, Wr1, HID, wf1);

    // ---- layer 0 (reads fp32 x directly) ----
    k_projmm0<<<M_PAD / 64, 512, 0, stream>>>(x, wf0, bl0, ybuf, rbuf);
    k_aggb<<<N_NODES / 16, 256, 0, stream>>>(ybuf, rbuf, offsets, ssrc, h0);

    // ---- layer 1 (fragments straight from global, no LDS) ----
    k_projmm1<<<M_PAD / 64, 512, 0, stream>>>(h0, wf1, bl1, ybuf, rbuf);
    k_aggb<<<N_NODES / 16, 256, 0, stream>>>(ybuf, rbuf, offsets, ssrc, h1);

    // ---- layer 2 ----
    k_proj2b<<<N_NODES / 4, 256, 0, stream>>>(h1, Wl2, Wr2, bl2, z, r2);
    k_agg2<<<(N_NODES + 255) / 256, 256, 0, stream>>>(z, r2, offsets, ssrc, out);
}

// Round 7
// 243.156 us; speedup vs baseline: 1.0142x; 1.0142x over previous
//
#include <hip/hip_runtime.h>

#define N_NODES 100000
#define N_EDGES 1000000
#define IN_CH 166
#define HID 128
#define M_PAD 100032   // 1563 * 64
#define NTILE 1563     // M_PAD / 64
#define NBLK 512       // persistent blocks for projections (2 per CU)
#define BSHIFT 9
#define NBUCK 196      // ceil(100000 / 512)

typedef unsigned short u16;
typedef unsigned int u32;
typedef __attribute__((ext_vector_type(8))) short short8;
typedef __attribute__((ext_vector_type(4))) float f32x4;

static __device__ __forceinline__ u16 f2bf(float f) {
    unsigned u = __float_as_uint(f);
    u += 0x7FFF + ((u >> 16) & 1);   // RNE
    return (u16)(u >> 16);
}
static __device__ __forceinline__ unsigned pk2(float a, float b) {
    return (unsigned)f2bf(a) | ((unsigned)f2bf(b) << 16);
}
static __device__ __forceinline__ float bf_lo(unsigned w) {
    return __uint_as_float(w << 16);
}
static __device__ __forceinline__ float bf_hi(unsigned w) {
    return __uint_as_float(w & 0xFFFF0000u);
}

// ================= graph build: two-level counting sort =================

__global__ __launch_bounds__(256) void k_bincount(const int* __restrict__ dst,
                                                  int* __restrict__ bcnt) {
    __shared__ int cnt[NBUCK];
    const int t = threadIdx.x;
    if (t < NBUCK) cnt[t] = 0;
    __syncthreads();
#pragma unroll
    for (int j = 0; j < 4; ++j) {
        int e4 = blockIdx.x * 1024 + j * 256 + t;
        if (e4 < N_EDGES / 4) {
            int4 d = ((const int4*)dst)[e4];
            atomicAdd(&cnt[d.x >> BSHIFT], 1);
            atomicAdd(&cnt[d.y >> BSHIFT], 1);
            atomicAdd(&cnt[d.z >> BSHIFT], 1);
            atomicAdd(&cnt[d.w >> BSHIFT], 1);
        }
    }
    __syncthreads();
    if (t < NBUCK && cnt[t] > 0) atomicAdd(&bcnt[t], cnt[t]);
}

__global__ __launch_bounds__(256) void k_bucketscan(const int* __restrict__ bcnt,
                                                    int* __restrict__ bucket_base,
                                                    int* __restrict__ gcursor,
                                                    int* __restrict__ offsets) {
    __shared__ int ws[256];
    const int t = threadIdx.x;
    int loc = (t < NBUCK) ? bcnt[t] : 0;
    ws[t] = loc;
    __syncthreads();
    int val = loc;
    for (int stp = 1; stp < 256; stp <<= 1) {
        int other = (t >= stp) ? ws[t - stp] : 0;
        __syncthreads();
        val += other;
        ws[t] = val;
        __syncthreads();
    }
    int excl = val - loc;
    if (t < NBUCK) {
        bucket_base[t] = excl;
        gcursor[t] = excl;
    }
    if (t == 255) bucket_base[NBUCK] = val;
    if (t == 0) offsets[N_NODES] = N_EDGES;
}

// stage entry: (src << 9) | (dst & 511)
__global__ __launch_bounds__(256) void k_scatter(const int* __restrict__ src,
                                                 const int* __restrict__ dst,
                                                 int* __restrict__ gcursor,
                                                 u32* __restrict__ stage) {
    __shared__ int cnt[NBUCK];
    __shared__ int base[NBUCK];
    const int t = threadIdx.x;
    if (t < NBUCK) cnt[t] = 0;
    __syncthreads();

    int4 s4[4], d4[4];
    bool ok[4];
#pragma unroll
    for (int j = 0; j < 4; ++j) {
        int e4 = blockIdx.x * 1024 + j * 256 + t;
        ok[j] = (e4 < N_EDGES / 4);
        if (ok[j]) {
            s4[j] = ((const int4*)src)[e4];
            d4[j] = ((const int4*)dst)[e4];
            atomicAdd(&cnt[d4[j].x >> BSHIFT], 1);
            atomicAdd(&cnt[d4[j].y >> BSHIFT], 1);
            atomicAdd(&cnt[d4[j].z >> BSHIFT], 1);
            atomicAdd(&cnt[d4[j].w >> BSHIFT], 1);
        }
    }
    __syncthreads();
    if (t < NBUCK && cnt[t] > 0) base[t] = atomicAdd(&gcursor[t], cnt[t]);
    __syncthreads();

#pragma unroll
    for (int j = 0; j < 4; ++j) {
        if (ok[j]) {
            const int ss[4] = {s4[j].x, s4[j].y, s4[j].z, s4[j].w};
            const int dd[4] = {d4[j].x, d4[j].y, d4[j].z, d4[j].w};
#pragma unroll
            for (int q = 0; q < 4; ++q) {
                int b = dd[q] >> BSHIFT;
                int r = atomicSub(&cnt[b], 1) - 1;
                stage[base[b] + r] = ((u32)ss[q] << 9) | (u32)(dd[q] & 511);
            }
        }
    }
}

__global__ __launch_bounds__(256) void k_csr(const u32* __restrict__ stage,
                                             const int* __restrict__ bucket_base,
                                             int* __restrict__ offsets,
                                             int* __restrict__ ssrc) {
    __shared__ int cnt[512];
    __shared__ int ws[256];
    const int t = threadIdx.x;
    const int b = blockIdx.x;
    const int nb0 = b << BSHIFT;
    const int nn = min(512, N_NODES - nb0);
    const int e0 = bucket_base[b];
    const int m = bucket_base[b + 1] - e0;

    cnt[t] = 0;
    cnt[t + 256] = 0;
    __syncthreads();

    for (int i = t; i < m; i += 256) {
        u32 pr = stage[e0 + i];
        atomicAdd(&cnt[pr & 511], 1);
    }
    __syncthreads();

    int c0 = cnt[2 * t];
    int c1 = cnt[2 * t + 1];
    int loc = c0 + c1;
    ws[t] = loc;
    __syncthreads();
    int val = loc;
    for (int stp = 1; stp < 256; stp <<= 1) {
        int other = (t >= stp) ? ws[t - stp] : 0;
        __syncthreads();
        val += other;
        ws[t] = val;
        __syncthreads();
    }
    int p0 = e0 + (val - loc);
    int p1 = p0 + c0;
    if (2 * t < nn) offsets[nb0 + 2 * t] = p0;
    if (2 * t + 1 < nn) offsets[nb0 + 2 * t + 1] = p1;
    cnt[2 * t] = p0;
    cnt[2 * t + 1] = p1;
    __syncthreads();

    for (int i = t; i < m; i += 256) {
        u32 pr = stage[e0 + i];
        int p = atomicAdd(&cnt[pr & 511], 1);
        ssrc[p] = (int)(pr >> 9);
    }
}

// ---------------- weight prep: Wl|Wr -> bf16 MFMA fragments ----------------

__global__ __launch_bounds__(64) void k_wprep(const float* __restrict__ Wl,
                                              const float* __restrict__ Wr,
                                              int Kact, u16* __restrict__ wf) {
    int lane = threadIdx.x;
    int kt = blockIdx.x >> 4;
    int ct = blockIdx.x & 15;
    int col = ct * 16 + (lane & 15);
    const float* W = (col < 128) ? Wl : Wr;
    int wcol = col & 127;
    float v[8];
#pragma unroll
    for (int j = 0; j < 8; ++j) {
        int row = kt * 32 + (lane >> 4) * 8 + j;
        v[j] = (row < Kact) ? W[(size_t)row * 128 + wcol] : 0.f;
    }
    int4 o;
    o.x = pk2(v[0], v[1]);
    o.y = pk2(v[2], v[3]);
    o.z = pk2(v[4], v[5]);
    o.w = pk2(v[6], v[7]);
    *(int4*)(wf + ((size_t)blockIdx.x * 64 + lane) * 8) = o;
}

// ---------------- persistent MFMA projections --------------------------
// swapped operands: acc = mfma(bf, af, acc) -> lane&15 = node row,
// (lane>>4)*4+i = output col -> packed int2 stores.
// 8 waves: rg = wv&1 (32 rows), cg = wv>>1 (64 cols).
// Weight fragments live in registers for the whole kernel; x tiles are
// double-buffered in LDS with async-stage split (load early, write late).

template <int KP>
static __device__ __forceinline__ void tile_compute(const u16* sA,
                                                    const short8* bfr,
                                                    const float* __restrict__ bias,
                                                    u16* __restrict__ y,
                                                    u16* __restrict__ rb,
                                                    int n0, int rg, int cg,
                                                    int r16, int kq) {
    constexpr int STR = KP + 8;
    f32x4 acc[2][4];
#pragma unroll
    for (int a = 0; a < 2; ++a)
#pragma unroll
        for (int b = 0; b < 4; ++b) acc[a][b] = (f32x4){0.f, 0.f, 0.f, 0.f};

#pragma unroll
    for (int kt = 0; kt < KP / 32; ++kt) {
        short8 af[2];
#pragma unroll
        for (int rt = 0; rt < 2; ++rt)
            af[rt] = *(const short8*)(&sA[(rg * 32 + rt * 16 + r16) * STR + kt * 32 + kq * 8]);
#pragma unroll
        for (int rt = 0; rt < 2; ++rt)
#pragma unroll
            for (int c = 0; c < 4; ++c)
                acc[rt][c] = __builtin_amdgcn_mfma_f32_16x16x32_bf16(bfr[kt * 4 + c], af[rt], acc[rt][c], 0, 0, 0);
    }

    if (cg < 2) {
#pragma unroll
        for (int rt = 0; rt < 2; ++rt) {
            size_t node = (size_t)(n0 + rg * 32 + rt * 16 + r16);
#pragma unroll
            for (int c = 0; c < 4; ++c) {
                int col = cg * 64 + c * 16 + kq * 4;
                int2 ov;
                ov.x = pk2(acc[rt][c][0], acc[rt][c][1]);
                ov.y = pk2(acc[rt][c][2], acc[rt][c][3]);
                *(int2*)(y + node * 128 + col) = ov;
            }
        }
    } else {
#pragma unroll
        for (int rt = 0; rt < 2; ++rt) {
            size_t node = (size_t)(n0 + rg * 32 + rt * 16 + r16);
#pragma unroll
            for (int c = 0; c < 4; ++c) {
                int col = (cg - 2) * 64 + c * 16 + kq * 4;
                float4 bv = *(const float4*)&bias[col];
                int2 ov;
                ov.x = pk2(acc[rt][c][0] + bv.x, acc[rt][c][1] + bv.y);
                ov.y = pk2(acc[rt][c][2] + bv.z, acc[rt][c][3] + bv.w);
                *(int2*)(rb + node * 128 + col) = ov;
            }
        }
    }
}

// layer 0: fp32 x [N,166], K padded to 192; stage = 6 x (2 float2) / thread
__global__ __launch_bounds__(512, 2) void k_projmm0(const float* __restrict__ in,
                                                    const u16* __restrict__ wf,
                                                    const float* __restrict__ bias,
                                                    u16* __restrict__ y,
                                                    u16* __restrict__ rb) {
    constexpr int KP = 192;
    constexpr int STR = KP + 8;
    constexpr int NKT = KP / 32;   // 6
    __shared__ u16 sA[2][64 * STR];
    const int tid = threadIdx.x;
    const int wv = tid >> 6;
    const int lane = tid & 63;
    const int rg = wv & 1;
    const int cg = wv >> 1;
    const int r16 = lane & 15;
    const int kq = lane >> 4;

    // weight fragments: registers for the whole kernel
    short8 bfr[NKT * 4];
#pragma unroll
    for (int kt = 0; kt < NKT; ++kt)
#pragma unroll
        for (int c = 0; c < 4; ++c)
            bfr[kt * 4 + c] = *(const short8*)(wf + (((size_t)(kt * 16 + cg * 4 + c) * 64 + lane) * 8));

    float2 a[6], b[6];
    auto stage_load = [&](int tile) {
        int n0 = tile * 64;
#pragma unroll
        for (int it = 0; it < 6; ++it) {
            int c = it * 512 + tid;
            int row = c / 48;
            int unit = c - row * 48;
            int gr = n0 + row;
            a[it] = {0.f, 0.f};
            b[it] = {0.f, 0.f};
            if (gr < N_NODES) {
                int k0 = unit * 4;
                const float* rp = in + (size_t)gr * IN_CH + k0;
                if (k0 + 3 < IN_CH) {
                    a[it] = *(const float2*)rp;
                    b[it] = *(const float2*)(rp + 2);
                } else if (k0 < IN_CH) {
                    a[it] = *(const float2*)rp;
                }
            }
        }
    };
    auto stage_write = [&](u16* sbuf) {
#pragma unroll
        for (int it = 0; it < 6; ++it) {
            int c = it * 512 + tid;
            int row = c / 48;
            int unit = c - row * 48;
            int2 o;
            o.x = pk2(a[it].x, a[it].y);
            o.y = pk2(b[it].x, b[it].y);
            *(int2*)(&sbuf[row * STR + unit * 4]) = o;
        }
    };

    int t = blockIdx.x;
    stage_load(t);
    stage_write(sA[0]);
    __syncthreads();
    int cur = 0;
    for (; t < NTILE; t += NBLK) {
        int tn = t + NBLK;
        bool hasnext = tn < NTILE;
        if (hasnext) stage_load(tn);                       // issue early
        tile_compute<KP>(sA[cur], bfr, bias, y, rb, t * 64, rg, cg, r16, kq);
        if (hasnext) stage_write(sA[cur ^ 1]);             // write late
        __syncthreads();
        cur ^= 1;
    }
}

// layer 1: bf16 input [M_PAD,128]; stage = 2 int4 / thread
__global__ __launch_bounds__(512, 2) void k_projmm1(const u16* __restrict__ in,
                                                    const u16* __restrict__ wf,
                                                    const float* __restrict__ bias,
                                                    u16* __restrict__ y,
                                                    u16* __restrict__ rb) {
    constexpr int KP = 128;
    constexpr int STR = KP + 8;
    constexpr int NKT = KP / 32;   // 4
    __shared__ u16 sA[2][64 * STR];
    const int tid = threadIdx.x;
    const int wv = tid >> 6;
    const int lane = tid & 63;
    const int rg = wv & 1;
    const int cg = wv >> 1;
    const int r16 = lane & 15;
    const int kq = lane >> 4;

    short8 bfr[NKT * 4];
#pragma unroll
    for (int kt = 0; kt < NKT; ++kt)
#pragma unroll
        for (int c = 0; c < 4; ++c)
            bfr[kt * 4 + c] = *(const short8*)(wf + (((size_t)(kt * 16 + cg * 4 + c) * 64 + lane) * 8));

    int4 v[2];
    auto stage_load = [&](int tile) {
        int n0 = tile * 64;
#pragma unroll
        for (int it = 0; it < 2; ++it) {
            int c = it * 512 + tid;
            int row = c >> 4;
            int cc = c & 15;
            v[it] = *(const int4*)(in + (size_t)(n0 + row) * KP + cc * 8);
        }
    };
    auto stage_write = [&](u16* sbuf) {
#pragma unroll
        for (int it = 0; it < 2; ++it) {
            int c = it * 512 + tid;
            int row = c >> 4;
            int cc = c & 15;
            *(int4*)(&sbuf[row * STR + cc * 8]) = v[it];
        }
    };

    int t = blockIdx.x;
    stage_load(t);
    stage_write(sA[0]);
    __syncthreads();
    int cur = 0;
    for (; t < NTILE; t += NBLK) {
        int tn = t + NBLK;
        bool hasnext = tn < NTILE;
        if (hasnext) stage_load(tn);
        tile_compute<KP>(sA[cur], bfr, bias, y, rb, t * 64, rg, cg, r16, kq);
        if (hasnext) stage_write(sA[cur ^ 1]);
        __syncthreads();
        cur ^= 1;
    }
}

// ---------------- aggregation: h = relu(mean_gather(yb) + rb), bf16 -------

__global__ __launch_bounds__(256) void k_aggb(const u16* __restrict__ yb,
                                              const u16* __restrict__ rb,
                                              const int* __restrict__ offsets,
                                              const int* __restrict__ ssrc,
                                              u16* __restrict__ h) {
    const int lane = threadIdx.x & 63;
    const int wv = threadIdx.x >> 6;
    const int g = lane >> 4;
    const int i = lane & 15;
    const int node = blockIdx.x * 16 + wv * 4 + g;
    const int off0 = offsets[node];
    const int deg = offsets[node + 1] - off0;

    float acc[8] = {0.f, 0.f, 0.f, 0.f, 0.f, 0.f, 0.f, 0.f};

    int e = 0;
    for (; e + 1 < deg; e += 2) {
        int s0 = ssrc[off0 + e];
        int s1 = ssrc[off0 + e + 1];
        int4 v0 = *(const int4*)(yb + (size_t)s0 * 128 + i * 8);
        int4 v1 = *(const int4*)(yb + (size_t)s1 * 128 + i * 8);
        const unsigned* w0 = (const unsigned*)&v0;
        const unsigned* w1 = (const unsigned*)&v1;
#pragma unroll
        for (int q = 0; q < 4; ++q) {
            acc[q * 2]     += bf_lo(w0[q]) + bf_lo(w1[q]);
            acc[q * 2 + 1] += bf_hi(w0[q]) + bf_hi(w1[q]);
        }
    }
    if (e < deg) {
        int s0 = ssrc[off0 + e];
        int4 v0 = *(const int4*)(yb + (size_t)s0 * 128 + i * 8);
        const unsigned* w0 = (const unsigned*)&v0;
#pragma unroll
        for (int q = 0; q < 4; ++q) {
            acc[q * 2]     += bf_lo(w0[q]);
            acc[q * 2 + 1] += bf_hi(w0[q]);
        }
    }

    float inv = 1.f / (float)max(deg, 1);
    int4 rv = *(const int4*)(rb + (size_t)node * 128 + i * 8);
    const unsigned* rw = (const unsigned*)&rv;
    float o[8];
#pragma unroll
    for (int q = 0; q < 4; ++q) {
        o[q * 2]     = fmaxf(acc[q * 2] * inv + bf_lo(rw[q]), 0.f);
        o[q * 2 + 1] = fmaxf(acc[q * 2 + 1] * inv + bf_hi(rw[q]), 0.f);
    }
    int4 ov;
    ov.x = pk2(o[0], o[1]);
    ov.y = pk2(o[2], o[3]);
    ov.z = pk2(o[4], o[5]);
    ov.w = pk2(o[6], o[7]);
    *(int4*)(h + (size_t)node * 128 + i * 8) = ov;
}

// ---------------- layer 2 projection (bf16 h -> 2ch) ----------------

__global__ __launch_bounds__(256) void k_proj2b(const u16* __restrict__ h,
                                                const float* __restrict__ Wl,
                                                const float* __restrict__ Wr,
                                                const float* __restrict__ bias,
                                                float* __restrict__ z,
                                                float* __restrict__ r2) {
    const int lane = threadIdx.x & 63;
    const int node = blockIdx.x * 4 + (threadIdx.x >> 6);
    unsigned hv = *(const unsigned*)(h + (size_t)node * 128 + lane * 2);
    float h0 = bf_lo(hv);
    float h1 = bf_hi(hv);
    float4 wl = *(const float4*)&Wl[lane * 4];
    float4 wr = *(const float4*)&Wr[lane * 4];
    float zl0 = h0 * wl.x + h1 * wl.z;
    float zl1 = h0 * wl.y + h1 * wl.w;
    float zr0 = h0 * wr.x + h1 * wr.z;
    float zr1 = h0 * wr.y + h1 * wr.w;
    for (int d = 32; d; d >>= 1) {
        zl0 += __shfl_xor(zl0, d);
        zl1 += __shfl_xor(zl1, d);
        zr0 += __shfl_xor(zr0, d);
        zr1 += __shfl_xor(zr1, d);
    }
    if (lane == 0) {
        z[node * 2 + 0] = zl0;
        z[node * 2 + 1] = zl1;
        r2[node * 2 + 0] = zr0 + bias[0];
        r2[node * 2 + 1] = zr1 + bias[1];
    }
}

// ---------------- layer 2 aggregation (2 channels) ----------------

__global__ __launch_bounds__(256) void k_agg2(const float* __restrict__ z,
                                              const float* __restrict__ r2,
                                              const int* __restrict__ offsets,
                                              const int* __restrict__ ssrc,
                                              float* __restrict__ out) {
    int n = blockIdx.x * 256 + threadIdx.x;
    if (n >= N_NODES) return;
    int off0 = offsets[n];
    int off1 = offsets[n + 1];
    float a0 = 0.f, a1 = 0.f;
    for (int e = off0; e < off1; ++e) {
        int s = ssrc[e];
        a0 += z[s * 2];
        a1 += z[s * 2 + 1];
    }
    float inv = 1.0f / (float)max(off1 - off0, 1);
    out[n * 2 + 0] = a0 * inv + r2[n * 2 + 0];
    out[n * 2 + 1] = a1 * inv + r2[n * 2 + 1];
}

// ---------------- launcher ----------------

extern "C" void kernel_launch(void* const* d_in, const int* in_sizes, int n_in,
                              void* d_out, int out_size, void* d_ws, size_t ws_size,
                              hipStream_t stream) {
    const float* x   = (const float*)d_in[0];
    const int*   ei  = (const int*)d_in[1];
    const float* Wl0 = (const float*)d_in[2];
    const float* bl0 = (const float*)d_in[3];
    const float* Wr0 = (const float*)d_in[4];
    const float* Wl1 = (const float*)d_in[5];
    const float* bl1 = (const float*)d_in[6];
    const float* Wr1 = (const float*)d_in[7];
    const float* Wl2 = (const float*)d_in[8];
    const float* bl2 = (const float*)d_in[9];
    const float* Wr2 = (const float*)d_in[10];
    float* out = (float*)d_out;

    const int* srcp = ei;
    const int* dstp = ei + N_EDGES;

    char* ws = (char*)d_ws;
    size_t off = 0;
    auto alloc = [&](size_t bytes) -> void* {
        void* p = ws + off;
        off += (bytes + 255) & ~(size_t)255;
        return p;
    };
    int* bcnt        = (int*)alloc(NBUCK * 4);
    int* bucket_base = (int*)alloc((NBUCK + 1) * 4);
    int* gcursor     = (int*)alloc(NBUCK * 4);
    int* offsets     = (int*)alloc((size_t)(N_NODES + 1) * 4);
    u32* stage       = (u32*)alloc((size_t)N_EDGES * 4);
    int* ssrc        = (int*)alloc((size_t)N_EDGES * 4);
    u16* wf0         = (u16*)alloc((size_t)192 * 256 * 2);
    u16* wf1         = (u16*)alloc((size_t)128 * 256 * 2);
    u16* ybuf        = (u16*)alloc((size_t)M_PAD * 128 * 2);
    u16* rbuf        = (u16*)alloc((size_t)M_PAD * 128 * 2);
    u16* h0          = (u16*)alloc((size_t)M_PAD * 128 * 2);
    u16* h1          = (u16*)alloc((size_t)M_PAD * 128 * 2);
    (void)ws_size; (void)n_in; (void)in_sizes; (void)out_size;

    float* z  = (float*)ybuf;                      // dead after layer-1 aggb
    float* r2 = (float*)((char*)ybuf + 1048576);

    // ---- graph build (two-level counting sort -> CSR by dst) ----
    hipMemsetAsync(bcnt, 0, NBUCK * 4, stream);
    const int NB_SC = (N_EDGES / 4 + 1023) / 1024;   // 245
    k_bincount<<<NB_SC, 256, 0, stream>>>(dstp, bcnt);
    k_bucketscan<<<1, 256, 0, stream>>>(bcnt, bucket_base, gcursor, offsets);
    k_scatter<<<NB_SC, 256, 0, stream>>>(srcp, dstp, gcursor, stage);
    k_csr<<<NBUCK, 256, 0, stream>>>(stage, bucket_base, offsets, ssrc);

    // ---- weight conversion ----
    k_wprep<<<(192 / 32) * 16, 64, 0, stream>>>(Wl0, Wr0, IN_CH, wf0);
    k_wprep<<<(128 / 32) * 16, 64, 0, stream>>>(Wl1, Wr1, HID, wf1);

    // ---- layer 0 (persistent, double-buffered, weights in regs) ----
    k_projmm0<<<NBLK, 512, 0, stream>>>(x, wf0, bl0, ybuf, rbuf);
    k_aggb<<<N_NODES / 16, 256, 0, stream>>>(ybuf, rbuf, offsets, ssrc, h0);

    // ---- layer 1 ----
    k_projmm1<<<NBLK, 512, 0, stream>>>(h0, wf1, bl1, ybuf, rbuf);
    k_aggb<<<N_NODES / 16, 256, 0, stream>>>(ybuf, rbuf, offsets, ssrc, h1);

    // ---- layer 2 ----
    k_proj2b<<<N_NODES / 4, 256, 0, stream>>>(h1, Wl2, Wr2, bl2, z, r2);
    k_agg2<<<(N_NODES + 255) / 256, 256, 0, stream>>>(z, r2, offsets, ssrc, out);
}

// Round 9
// 221.629 us; speedup vs baseline: 1.1127x; 1.0971x over previous
//
#include <hip/hip_runtime.h>

#define N_NODES 100000
#define N_EDGES 1000000
#define IN_CH 166
#define HID 128
#define M_PAD 100032   // 1563 * 64
#define NTILE 1563
#define BSHIFT 9
#define NBUCK 196

typedef unsigned short u16;
typedef unsigned int u32;
typedef __attribute__((ext_vector_type(8))) short short8;
typedef __attribute__((ext_vector_type(4))) float f32x4;

static __device__ __forceinline__ u16 f2bf(float f) {
    unsigned u = __float_as_uint(f);
    u += 0x7FFF + ((u >> 16) & 1);   // RNE
    return (u16)(u >> 16);
}
static __device__ __forceinline__ unsigned pk2(float a, float b) {
    return (unsigned)f2bf(a) | ((unsigned)f2bf(b) << 16);
}
static __device__ __forceinline__ float bf_lo(unsigned w) {
    return __uint_as_float(w << 16);
}
static __device__ __forceinline__ float bf_hi(unsigned w) {
    return __uint_as_float(w & 0xFFFF0000u);
}

// ================= graph build: two-level counting sort =================

__global__ __launch_bounds__(256) void k_bincount(const int* __restrict__ dst,
                                                  int* __restrict__ bcnt) {
    __shared__ int cnt[NBUCK];
    const int t = threadIdx.x;
    if (t < NBUCK) cnt[t] = 0;
    __syncthreads();
#pragma unroll
    for (int j = 0; j < 4; ++j) {
        int e4 = blockIdx.x * 1024 + j * 256 + t;
        if (e4 < N_EDGES / 4) {
            int4 d = ((const int4*)dst)[e4];
            atomicAdd(&cnt[d.x >> BSHIFT], 1);
            atomicAdd(&cnt[d.y >> BSHIFT], 1);
            atomicAdd(&cnt[d.z >> BSHIFT], 1);
            atomicAdd(&cnt[d.w >> BSHIFT], 1);
        }
    }
    __syncthreads();
    if (t < NBUCK && cnt[t] > 0) atomicAdd(&bcnt[t], cnt[t]);
}

__global__ __launch_bounds__(256) void k_bucketscan(const int* __restrict__ bcnt,
                                                    int* __restrict__ bucket_base,
                                                    int* __restrict__ gcursor,
                                                    int* __restrict__ offsets) {
    __shared__ int ws[256];
    const int t = threadIdx.x;
    int loc = (t < NBUCK) ? bcnt[t] : 0;
    ws[t] = loc;
    __syncthreads();
    int val = loc;
    for (int stp = 1; stp < 256; stp <<= 1) {
        int other = (t >= stp) ? ws[t - stp] : 0;
        __syncthreads();
        val += other;
        ws[t] = val;
        __syncthreads();
    }
    int excl = val - loc;
    if (t < NBUCK) {
        bucket_base[t] = excl;
        gcursor[t] = excl;
    }
    if (t == 255) bucket_base[NBUCK] = val;
    if (t == 0) offsets[N_NODES] = N_EDGES;
}

__global__ __launch_bounds__(256) void k_scatter(const int* __restrict__ src,
                                                 const int* __restrict__ dst,
                                                 int* __restrict__ gcursor,
                                                 u32* __restrict__ stage) {
    __shared__ int cnt[NBUCK];
    __shared__ int base[NBUCK];
    const int t = threadIdx.x;
    if (t < NBUCK) cnt[t] = 0;
    __syncthreads();

    int4 s4[4], d4[4];
    bool ok[4];
#pragma unroll
    for (int j = 0; j < 4; ++j) {
        int e4 = blockIdx.x * 1024 + j * 256 + t;
        ok[j] = (e4 < N_EDGES / 4);
        if (ok[j]) {
            s4[j] = ((const int4*)src)[e4];
            d4[j] = ((const int4*)dst)[e4];
            atomicAdd(&cnt[d4[j].x >> BSHIFT], 1);
            atomicAdd(&cnt[d4[j].y >> BSHIFT], 1);
            atomicAdd(&cnt[d4[j].z >> BSHIFT], 1);
            atomicAdd(&cnt[d4[j].w >> BSHIFT], 1);
        }
    }
    __syncthreads();
    if (t < NBUCK && cnt[t] > 0) base[t] = atomicAdd(&gcursor[t], cnt[t]);
    __syncthreads();

#pragma unroll
    for (int j = 0; j < 4; ++j) {
        if (ok[j]) {
            const int ss[4] = {s4[j].x, s4[j].y, s4[j].z, s4[j].w};
            const int dd[4] = {d4[j].x, d4[j].y, d4[j].z, d4[j].w};
#pragma unroll
            for (int q = 0; q < 4; ++q) {
                int b = dd[q] >> BSHIFT;
                int r = atomicSub(&cnt[b], 1) - 1;
                stage[base[b] + r] = ((u32)ss[q] << 9) | (u32)(dd[q] & 511);
            }
        }
    }
}

__global__ __launch_bounds__(256) void k_csr(const u32* __restrict__ stage,
                                             const int* __restrict__ bucket_base,
                                             int* __restrict__ offsets,
                                             int* __restrict__ ssrc) {
    __shared__ int cnt[512];
    __shared__ int ws[256];
    const int t = threadIdx.x;
    const int b = blockIdx.x;
    const int nb0 = b << BSHIFT;
    const int nn = min(512, N_NODES - nb0);
    const int e0 = bucket_base[b];
    const int m = bucket_base[b + 1] - e0;

    cnt[t] = 0;
    cnt[t + 256] = 0;
    __syncthreads();

    for (int i = t; i < m; i += 256) {
        u32 pr = stage[e0 + i];
        atomicAdd(&cnt[pr & 511], 1);
    }
    __syncthreads();

    int c0 = cnt[2 * t];
    int c1 = cnt[2 * t + 1];
    int loc = c0 + c1;
    ws[t] = loc;
    __syncthreads();
    int val = loc;
    for (int stp = 1; stp < 256; stp <<= 1) {
        int other = (t >= stp) ? ws[t - stp] : 0;
        __syncthreads();
        val += other;
        ws[t] = val;
        __syncthreads();
    }
    int p0 = e0 + (val - loc);
    int p1 = p0 + c0;
    if (2 * t < nn) offsets[nb0 + 2 * t] = p0;
    if (2 * t + 1 < nn) offsets[nb0 + 2 * t + 1] = p1;
    cnt[2 * t] = p0;
    cnt[2 * t + 1] = p1;
    __syncthreads();

    for (int i = t; i < m; i += 256) {
        u32 pr = stage[e0 + i];
        int p = atomicAdd(&cnt[pr & 511], 1);
        ssrc[p] = (int)(pr >> 9);
    }
}

// ---------------- weight prep: Wl|Wr -> bf16 MFMA fragments ----------------

__global__ __launch_bounds__(64) void k_wprep(const float* __restrict__ Wl,
                                              const float* __restrict__ Wr,
                                              int Kact, u16* __restrict__ wf) {
    int lane = threadIdx.x;
    int kt = blockIdx.x >> 4;
    int ct = blockIdx.x & 15;
    int col = ct * 16 + (lane & 15);
    const float* W = (col < 128) ? Wl : Wr;
    int wcol = col & 127;
    float v[8];
#pragma unroll
    for (int j = 0; j < 8; ++j) {
        int row = kt * 32 + (lane >> 4) * 8 + j;
        v[j] = (row < Kact) ? W[(size_t)row * 128 + wcol] : 0.f;
    }
    int4 o;
    o.x = pk2(v[0], v[1]);
    o.y = pk2(v[2], v[3]);
    o.z = pk2(v[4], v[5]);
    o.w = pk2(v[6], v[7]);
    *(int4*)(wf + ((size_t)blockIdx.x * 64 + lane) * 8) = o;
}

// ---------------- MFMA projection with LDS-transpose epilogue ------------
// swapped operands: acc = mfma(bf, af, acc) -> lane&15 = node row,
// (lane>>4)*4+i = output col. Epilogue: acc -> LDS [64][136] -> coalesced
// int4 stores (full cachelines): 64 rows x 16 chunks = 1024 int4 per phase.

#define STR2 136

template <int KP>
static __device__ __forceinline__ void proj_tail(const u16* __restrict__ wf,
                                                 const float* __restrict__ bias,
                                                 u16* __restrict__ y,
                                                 u16* __restrict__ rb,
                                                 u16* sA, int n0) {
    constexpr int STR = KP + 8;
    const int tid = threadIdx.x;
    const int wv = tid >> 6;
    const int lane = tid & 63;
    const int rg = wv & 1;
    const int cg = wv >> 1;
    const int r16 = lane & 15;
    const int kq = lane >> 4;

    f32x4 acc[2][4];
#pragma unroll
    for (int a = 0; a < 2; ++a)
#pragma unroll
        for (int b = 0; b < 4; ++b) acc[a][b] = (f32x4){0.f, 0.f, 0.f, 0.f};

#pragma unroll
    for (int kt = 0; kt < KP / 32; ++kt) {
        short8 af[2], bf[4];
#pragma unroll
        for (int rt = 0; rt < 2; ++rt)
            af[rt] = *(const short8*)(&sA[(rg * 32 + rt * 16 + r16) * STR + kt * 32 + kq * 8]);
#pragma unroll
        for (int c = 0; c < 4; ++c)
            bf[c] = *(const short8*)(wf + (((size_t)(kt * 16 + cg * 4 + c) * 64 + lane) * 8));
#pragma unroll
        for (int rt = 0; rt < 2; ++rt)
#pragma unroll
            for (int c = 0; c < 4; ++c)
                acc[rt][c] = __builtin_amdgcn_mfma_f32_16x16x32_bf16(bf[c], af[rt], acc[rt][c], 0, 0, 0);
    }

    // ---- phase Y: cols 0..127 -> LDS -> coalesced stores ----
    __syncthreads();   // sA staging dead
    if (cg < 2) {
#pragma unroll
        for (int rt = 0; rt < 2; ++rt) {
            int row = rg * 32 + rt * 16 + r16;
#pragma unroll
            for (int c = 0; c < 4; ++c) {
                int col = cg * 64 + c * 16 + kq * 4;
                int2 ov;
                ov.x = pk2(acc[rt][c][0], acc[rt][c][1]);
                ov.y = pk2(acc[rt][c][2], acc[rt][c][3]);
                *(int2*)(&sA[row * STR2 + col]) = ov;
            }
        }
    }
    __syncthreads();
#pragma unroll
    for (int p = 0; p < 2; ++p) {
        int c = p * 512 + tid;
        int row = c >> 4;      // 64 rows
        int ch = c & 15;       // 16 int4 chunks (128 u16) per row
        int4 v = *(const int4*)(&sA[row * STR2 + ch * 8]);
        *(int4*)(y + (size_t)(n0 + row) * 128 + ch * 8) = v;
    }
    // ---- phase R: cols 128..255 (+bias) ----
    __syncthreads();
    if (cg >= 2) {
#pragma unroll
        for (int rt = 0; rt < 2; ++rt) {
            int row = rg * 32 + rt * 16 + r16;
#pragma unroll
            for (int c = 0; c < 4; ++c) {
                int col = (cg - 2) * 64 + c * 16 + kq * 4;
                float4 bv = *(const float4*)&bias[col];
                int2 ov;
                ov.x = pk2(acc[rt][c][0] + bv.x, acc[rt][c][1] + bv.y);
                ov.y = pk2(acc[rt][c][2] + bv.z, acc[rt][c][3] + bv.w);
                *(int2*)(&sA[row * STR2 + col]) = ov;
            }
        }
    }
    __syncthreads();
#pragma unroll
    for (int p = 0; p < 2; ++p) {
        int c = p * 512 + tid;
        int row = c >> 4;
        int ch = c & 15;
        int4 v = *(const int4*)(&sA[row * STR2 + ch * 8]);
        *(int4*)(rb + (size_t)(n0 + row) * 128 + ch * 8) = v;
    }
}

// layer 0: fp32 x [N,166]; tile = exactly 2656 aligned float4 (64*166/4)
__global__ __launch_bounds__(512, 4) void k_projmm0(const float* __restrict__ in,
                                                    const u16* __restrict__ wf,
                                                    const float* __restrict__ bias,
                                                    u16* __restrict__ y,
                                                    u16* __restrict__ rb) {
    constexpr int KP = 192;
    constexpr int STR = KP + 8;   // 200
    __shared__ u16 sA[64 * STR];  // 25.6 KB
    const int tid = threadIdx.x;
    const int n0 = blockIdx.x * 64;

    // zero-fill K pad cols 166..191
    for (int c = tid; c < 64 * 26; c += 512) {
        int row = c / 26;
        int col = 166 + (c - row * 26);
        sA[row * STR + col] = 0;
    }
    // zero-fill padding node rows of the last tile (cols 0..165)
    if (n0 + 63 >= N_NODES) {
        for (int c = tid; c < 64 * 166; c += 512) {
            int row = c / 166;
            if (n0 + row >= N_NODES) sA[row * STR + (c - row * 166)] = 0;
        }
    }
    // flat float4 staging: element e = f*4+j -> (row=e/166, k=e%166)
    const float4* x4 = (const float4*)in;
    const size_t gbase = (size_t)blockIdx.x * 2656;
#pragma unroll
    for (int it = 0; it < 6; ++it) {
        int f = it * 512 + tid;
        size_t gf = gbase + f;
        if (f < 2656 && gf < (size_t)N_NODES * IN_CH / 4) {
            float4 v = x4[gf];
            int e0 = f * 4;
            int row = e0 / IN_CH;
            int k = e0 - row * IN_CH;
            const float vv[4] = {v.x, v.y, v.z, v.w};
#pragma unroll
            for (int j = 0; j < 4; ++j) {
                int kk = k + j;
                int r = row, c = kk;
                if (kk >= IN_CH) { r = row + 1; c = kk - IN_CH; }
                sA[r * STR + c] = f2bf(vv[j]);
            }
        }
    }
    __syncthreads();
    proj_tail<KP>(wf, bias, y, rb, sA, n0);
}

// layer 1: bf16 input [M_PAD,128]
__global__ __launch_bounds__(512, 4) void k_projmm1(const u16* __restrict__ in,
                                                    const u16* __restrict__ wf,
                                                    const float* __restrict__ bias,
                                                    u16* __restrict__ y,
                                                    u16* __restrict__ rb) {
    constexpr int KP = 128;
    constexpr int STR = KP + 8;   // 136
    __shared__ u16 sA[64 * STR];  // 17.4 KB
    const int tid = threadIdx.x;
    const int n0 = blockIdx.x * 64;

#pragma unroll
    for (int it = 0; it < 2; ++it) {
        int c = it * 512 + tid;
        int row = c >> 4;
        int cc = c & 15;
        int4 v = *(const int4*)(in + (size_t)(n0 + row) * KP + cc * 8);
        *(int4*)(&sA[row * STR + cc * 8]) = v;
    }
    __syncthreads();
    proj_tail<KP>(wf, bias, y, rb, sA, n0);
}

// ---------------- aggregation: h = relu(mean_gather(yb) + rb), bf16 -------
// one 16-lane group per node; 4-edge unroll for gather MLP.

__global__ __launch_bounds__(256) void k_aggb(const u16* __restrict__ yb,
                                              const u16* __restrict__ rb,
                                              const int* __restrict__ offsets,
                                              const int* __restrict__ ssrc,
                                              u16* __restrict__ h) {
    const int lane = threadIdx.x & 63;
    const int wv = threadIdx.x >> 6;
    const int g = lane >> 4;
    const int i = lane & 15;
    const int node = blockIdx.x * 16 + wv * 4 + g;
    const int off0 = offsets[node];
    const int deg = offsets[node + 1] - off0;

    float acc[8] = {0.f, 0.f, 0.f, 0.f, 0.f, 0.f, 0.f, 0.f};

    int e = 0;
    for (; e + 3 < deg; e += 4) {
        int s0 = ssrc[off0 + e];
        int s1 = ssrc[off0 + e + 1];
        int s2 = ssrc[off0 + e + 2];
        int s3 = ssrc[off0 + e + 3];
        int4 v0 = *(const int4*)(yb + (size_t)s0 * 128 + i * 8);
        int4 v1 = *(const int4*)(yb + (size_t)s1 * 128 + i * 8);
        int4 v2 = *(const int4*)(yb + (size_t)s2 * 128 + i * 8);
        int4 v3 = *(const int4*)(yb + (size_t)s3 * 128 + i * 8);
        const unsigned* w0 = (const unsigned*)&v0;
        const unsigned* w1 = (const unsigned*)&v1;
        const unsigned* w2 = (const unsigned*)&v2;
        const unsigned* w3 = (const unsigned*)&v3;
#pragma unroll
        for (int q = 0; q < 4; ++q) {
            acc[q * 2]     += (bf_lo(w0[q]) + bf_lo(w1[q])) + (bf_lo(w2[q]) + bf_lo(w3[q]));
            acc[q * 2 + 1] += (bf_hi(w0[q]) + bf_hi(w1[q])) + (bf_hi(w2[q]) + bf_hi(w3[q]));
        }
    }
    for (; e < deg; ++e) {
        int s0 = ssrc[off0 + e];
        int4 v0 = *(const int4*)(yb + (size_t)s0 * 128 + i * 8);
        const unsigned* w0 = (const unsigned*)&v0;
#pragma unroll
        for (int q = 0; q < 4; ++q) {
            acc[q * 2]     += bf_lo(w0[q]);
            acc[q * 2 + 1] += bf_hi(w0[q]);
        }
    }

    float inv = 1.f / (float)max(deg, 1);
    int4 rv = *(const int4*)(rb + (size_t)node * 128 + i * 8);
    const unsigned* rw = (const unsigned*)&rv;
    float o[8];
#pragma unroll
    for (int q = 0; q < 4; ++q) {
        o[q * 2]     = fmaxf(acc[q * 2] * inv + bf_lo(rw[q]), 0.f);
        o[q * 2 + 1] = fmaxf(acc[q * 2 + 1] * inv + bf_hi(rw[q]), 0.f);
    }
    int4 ov;
    ov.x = pk2(o[0], o[1]);
    ov.y = pk2(o[2], o[3]);
    ov.z = pk2(o[4], o[5]);
    ov.w = pk2(o[6], o[7]);
    *(int4*)(h + (size_t)node * 128 + i * 8) = ov;
}

// ---------------- layer 2 projection (bf16 h -> 2ch) ----------------

__global__ __launch_bounds__(256) void k_proj2b(const u16* __restrict__ h,
                                                const float* __restrict__ Wl,
                                                const float* __restrict__ Wr,
                                                const float* __restrict__ bias,
                                                float* __restrict__ z,
                                                float* __restrict__ r2) {
    const int lane = threadIdx.x & 63;
    const int node = blockIdx.x * 4 + (threadIdx.x >> 6);
    unsigned hv = *(const unsigned*)(h + (size_t)node * 128 + lane * 2);
    float h0 = bf_lo(hv);
    float h1 = bf_hi(hv);
    float4 wl = *(const float4*)&Wl[lane * 4];
    float4 wr = *(const float4*)&Wr[lane * 4];
    float zl0 = h0 * wl.x + h1 * wl.z;
    float zl1 = h0 * wl.y + h1 * wl.w;
    float zr0 = h0 * wr.x + h1 * wr.z;
    float zr1 = h0 * wr.y + h1 * wr.w;
    for (int d = 32; d; d >>= 1) {
        zl0 += __shfl_xor(zl0, d);
        zl1 += __shfl_xor(zl1, d);
        zr0 += __shfl_xor(zr0, d);
        zr1 += __shfl_xor(zr1, d);
    }
    if (lane == 0) {
        z[node * 2 + 0] = zl0;
        z[node * 2 + 1] = zl1;
        r2[node * 2 + 0] = zr0 + bias[0];
        r2[node * 2 + 1] = zr1 + bias[1];
    }
}

// ---------------- layer 2 aggregation (2 channels) ----------------

__global__ __launch_bounds__(256) void k_agg2(const float* __restrict__ z,
                                              const float* __restrict__ r2,
                                              const int* __restrict__ offsets,
                                              const int* __restrict__ ssrc,
                                              float* __restrict__ out) {
    int n = blockIdx.x * 256 + threadIdx.x;
    if (n >= N_NODES) return;
    int off0 = offsets[n];
    int off1 = offsets[n + 1];
    float a0 = 0.f, a1 = 0.f;
    for (int e = off0; e < off1; ++e) {
        int s = ssrc[e];
        a0 += z[s * 2];
        a1 += z[s * 2 + 1];
    }
    float inv = 1.0f / (float)max(off1 - off0, 1);
    out[n * 2 + 0] = a0 * inv + r2[n * 2 + 0];
    out[n * 2 + 1] = a1 * inv + r2[n * 2 + 1];
}

// ---------------- launcher ----------------

extern "C" void kernel_launch(void* const* d_in, const int* in_sizes, int n_in,
                              void* d_out, int out_size, void* d_ws, size_t ws_size,
                              hipStream_t stream) {
    const float* x   = (const float*)d_in[0];
    const int*   ei  = (const int*)d_in[1];
    const float* Wl0 = (const float*)d_in[2];
    const float* bl0 = (const float*)d_in[3];
    const float* Wr0 = (const float*)d_in[4];
    const float* Wl1 = (const float*)d_in[5];
    const float* bl1 = (const float*)d_in[6];
    const float* Wr1 = (const float*)d_in[7];
    const float* Wl2 = (const float*)d_in[8];
    const float* bl2 = (const float*)d_in[9];
    const float* Wr2 = (const float*)d_in[10];
    float* out = (float*)d_out;

    const int* srcp = ei;
    const int* dstp = ei + N_EDGES;

    char* ws = (char*)d_ws;
    size_t off = 0;
    auto alloc = [&](size_t bytes) -> void* {
        void* p = ws + off;
        off += (bytes + 255) & ~(size_t)255;
        return p;
    };
    int* bcnt        = (int*)alloc(NBUCK * 4);
    int* bucket_base = (int*)alloc((NBUCK + 1) * 4);
    int* gcursor     = (int*)alloc(NBUCK * 4);
    int* offsets     = (int*)alloc((size_t)(N_NODES + 1) * 4);
    u32* stage       = (u32*)alloc((size_t)N_EDGES * 4);
    int* ssrc        = (int*)alloc((size_t)N_EDGES * 4);
    u16* wf0         = (u16*)alloc((size_t)192 * 256 * 2);
    u16* wf1         = (u16*)alloc((size_t)128 * 256 * 2);
    u16* ybuf        = (u16*)alloc((size_t)M_PAD * 128 * 2);
    u16* rbuf        = (u16*)alloc((size_t)M_PAD * 128 * 2);
    u16* h0          = (u16*)alloc((size_t)M_PAD * 128 * 2);
    u16* h1          = (u16*)alloc((size_t)M_PAD * 128 * 2);
    (void)ws_size; (void)n_in; (void)in_sizes; (void)out_size;

    float* z  = (float*)ybuf;                      // dead after layer-1 aggb
    float* r2 = (float*)((char*)ybuf + 1048576);

    // ---- graph build (two-level counting sort -> CSR by dst) ----
    hipMemsetAsync(bcnt, 0, NBUCK * 4, stream);
    const int NB_SC = (N_EDGES / 4 + 1023) / 1024;   // 245
    k_bincount<<<NB_SC, 256, 0, stream>>>(dstp, bcnt);
    k_bucketscan<<<1, 256, 0, stream>>>(bcnt, bucket_base, gcursor, offsets);
    k_scatter<<<NB_SC, 256, 0, stream>>>(srcp, dstp, gcursor, stage);
    k_csr<<<NBUCK, 256, 0, stream>>>(stage, bucket_base, offsets, ssrc);

    // ---- weight conversion ----
    k_wprep<<<(192 / 32) * 16, 64, 0, stream>>>(Wl0, Wr0, IN_CH, wf0);
    k_wprep<<<(128 / 32) * 16, 64, 0, stream>>>(Wl1, Wr1, HID, wf1);

    // ---- layer 0 ----
    k_projmm0<<<NTILE, 512, 0, stream>>>(x, wf0, bl0, ybuf, rbuf);
    k_aggb<<<N_NODES / 16, 256, 0, stream>>>(ybuf, rbuf, offsets, ssrc, h0);

    // ---- layer 1 ----
    k_projmm1<<<NTILE, 512, 0, stream>>>(h0, wf1, bl1, ybuf, rbuf);
    k_aggb<<<N_NODES / 16, 256, 0, stream>>>(ybuf, rbuf, offsets, ssrc, h1);

    // ---- layer 2 ----
    k_proj2b<<<N_NODES / 4, 256, 0, stream>>>(h1, Wl2, Wr2, bl2, z, r2);
    k_agg2<<<(N_NODES + 255) / 256, 256, 0, stream>>>(z, r2, offsets, ssrc, out);
}